// Round 2
// 251.725 us; speedup vs baseline: 1.0207x; 1.0207x over previous
//
#include <hip/hip_runtime.h>

typedef unsigned short u16;
typedef unsigned int u32;
using frag8 = __attribute__((ext_vector_type(8))) short;   // 8 x bf16 (4 VGPRs)
using f32x4 = __attribute__((ext_vector_type(4))) float;   // 16x16 MFMA accumulator

// ---------- helpers ----------
__device__ __forceinline__ u16 f2bf(float f) {
  union { float f; u32 u; } x;
  x.f = f;
  u32 r = (x.u + 0x7fffu + ((x.u >> 16) & 1u)) >> 16;  // RNE
  return (u16)r;
}

// Stage a 128x64 bf16 tile (row-major, k contiguous) global -> LDS via async
// global_load_lds, width 16B. 256 threads, 4 issues each. LDS dest must be
// wave-uniform base + lane*16 (hardware constraint) so the LDS image is
// lane-ordered; we XOR-swizzle WHICH global chunk each lane fetches
// (colc ^ row&7) to break the 128B-row-stride bank aliasing. frag_read64
// applies the same XOR to find its data.
__device__ __forceinline__ void stage_tile64(const u16* g, int ld, u16* lds, int tid) {
  const int wv = tid >> 6;
#pragma unroll
  for (int i = 0; i < 4; ++i) {
    const int c = i * 256 + tid;              // 16B chunk index, 1024 total
    const int row = c >> 3;                   // 8 chunks per 64-elem row
    const int colc = (c & 7) ^ (row & 7);     // swizzled source chunk
    __builtin_amdgcn_global_load_lds(
        (const __attribute__((address_space(1))) void*)(g + (size_t)row * ld + colc * 8),
        (__attribute__((address_space(3))) void*)(lds + (size_t)(i * 256 + wv * 64) * 8),
        16, 0, 0);
  }
}

// One block-wide staging issue for the 512-thread aft kernel: 64 rows x 64
// cols (8 KB) of a row-major ld=1024 bf16 source, same XOR swizzle scheme.
__device__ __forceinline__ void stage64(const u16* g, u16* l, int tid) {
  const int wv = tid >> 6;
  const int row = tid >> 3;                   // 0..63
  const int colc = (tid & 7) ^ (row & 7);     // swizzled source chunk
  __builtin_amdgcn_global_load_lds(
      (const __attribute__((address_space(1))) void*)(g + (size_t)row * 1024 + (size_t)colc * 8),
      (__attribute__((address_space(3))) void*)(l + (size_t)wv * 512),
      16, 0, 0);
}

// 16x16x32 A/B fragment from a swizzled Rx64 tile; kk selects k-half (0/1).
__device__ __forceinline__ frag8 frag_read64(const u16* lds, int row, int kk, int quad) {
  const int cc = (kk * 4 + quad) ^ (row & 7);
  return *(const frag8*)&lds[row * 64 + cc * 8];
}

// ---------- fused prep: bf16 casts of x, Wq, Wk, Wv + exp(pos_bias) ----------
// grid.x ranges: [0,16384) x | [16384,16640) Wq | [16640,16896) Wk |
// [16896,17152) Wv | [17152,18176) exp(pos_bias)
__global__ void prep_kernel(const float* __restrict__ x, const float* __restrict__ Wq,
                            const float* __restrict__ Wk, const float* __restrict__ Wv,
                            const float* __restrict__ pb, u16* __restrict__ xb,
                            u16* __restrict__ wqb, u16* __restrict__ wkb,
                            u16* __restrict__ wvb, u16* __restrict__ ewb) {
  const int blk = blockIdx.x;
  const float* src;
  u16* dst;
  int base;
  bool ex = false;
  if (blk < 16384)      { src = x;  dst = xb;  base = blk; }
  else if (blk < 16640) { src = Wq; dst = wqb; base = blk - 16384; }
  else if (blk < 16896) { src = Wk; dst = wkb; base = blk - 16640; }
  else if (blk < 17152) { src = Wv; dst = wvb; base = blk - 16896; }
  else                  { src = pb; dst = ewb; base = blk - 17152; ex = true; }
  const int i = base * 256 + threadIdx.x;
  float4 v = ((const float4*)src)[i];
  ushort4 o;
  if (ex) {
    o.x = f2bf(__expf(v.x)); o.y = f2bf(__expf(v.y));
    o.z = f2bf(__expf(v.z)); o.w = f2bf(__expf(v.w));
  } else {
    o.x = f2bf(v.x); o.y = f2bf(v.y); o.z = f2bf(v.z); o.w = f2bf(v.w);
  }
  ((ushort4*)dst)[i] = o;
}

// ---------- Q projection: out = sigmoid(x @ Wq^T + bq), written to d_out ----------
__global__ __launch_bounds__(256, 3) void q_kernel(const u16* __restrict__ xb,
                                                   const u16* __restrict__ wqb,
                                                   const float* __restrict__ bq,
                                                   float* __restrict__ out) {
  __shared__ __align__(16) u16 As[128 * 64];
  __shared__ __align__(16) u16 Bs[128 * 64];
  const int tid = threadIdx.x;
  const int lane = tid & 63, wv = tid >> 6;
  const int wm = (wv & 1) * 64, wn = (wv >> 1) * 64;
  const int fr = lane & 15, quad = lane >> 4;
  const int m0 = blockIdx.y * 128;   // rows over B*N = 32768
  const int n0 = blockIdx.x * 128;   // cols over D = 512
  f32x4 acc[4][4] = {};
  for (int k0 = 0; k0 < 512; k0 += 64) {
    stage_tile64(xb + (size_t)m0 * 512 + k0, 512, As, tid);
    stage_tile64(wqb + (size_t)n0 * 512 + k0, 512, Bs, tid);
    __syncthreads();
#pragma unroll
    for (int kk = 0; kk < 2; ++kk) {
      frag8 a[4], b[4];
#pragma unroll
      for (int i = 0; i < 4; ++i) {
        a[i] = frag_read64(As, wm + i * 16 + fr, kk, quad);
        b[i] = frag_read64(Bs, wn + i * 16 + fr, kk, quad);
      }
#pragma unroll
      for (int mi = 0; mi < 4; ++mi)
#pragma unroll
        for (int ni = 0; ni < 4; ++ni)
          acc[mi][ni] = __builtin_amdgcn_mfma_f32_16x16x32_bf16(a[mi], b[ni], acc[mi][ni], 0, 0, 0);
    }
    __syncthreads();
  }
#pragma unroll
  for (int mi = 0; mi < 4; ++mi)
#pragma unroll
    for (int ni = 0; ni < 4; ++ni) {
      const int col = n0 + wn + ni * 16 + fr;
      const float bqv = bq[col];
#pragma unroll
      for (int r = 0; r < 4; ++r) {
        const int row = m0 + wm + mi * 16 + quad * 4 + r;
        const float qv = acc[mi][ni][r] + bqv;
        out[(size_t)row * 512 + col] = 1.0f / (1.0f + __expf(-qv));
      }
    }
}

// ---------- K,V projection (transposed out): ekT/ekvT [b][d][s] bf16 ----------
__global__ __launch_bounds__(256, 2) void kv_kernel(const u16* __restrict__ xb,
                                                    const u16* __restrict__ wkb,
                                                    const u16* __restrict__ wvb,
                                                    const float* __restrict__ bk,
                                                    const float* __restrict__ bv,
                                                    u16* __restrict__ ekT,
                                                    u16* __restrict__ ekvT) {
  __shared__ __align__(16) u16 Ak[128 * 64];
  __shared__ __align__(16) u16 Av[128 * 64];
  __shared__ __align__(16) u16 Bs[128 * 64];
  const int tid = threadIdx.x;
  const int lane = tid & 63, wv = tid >> 6;
  const int wm = (wv & 1) * 64, wn = (wv >> 1) * 64;
  const int fr = lane & 15, quad = lane >> 4;
  const int s0 = blockIdx.x * 128;   // n: sequence pos (1024)
  const int d0 = blockIdx.y * 128;   // m: feature dim (512)
  const int b  = blockIdx.z;
  f32x4 acck[4][4] = {}, accv[4][4] = {};
  for (int k0 = 0; k0 < 512; k0 += 64) {
    stage_tile64(wkb + (size_t)d0 * 512 + k0, 512, Ak, tid);
    stage_tile64(wvb + (size_t)d0 * 512 + k0, 512, Av, tid);
    stage_tile64(xb + ((size_t)b * 1024 + s0) * 512 + k0, 512, Bs, tid);
    __syncthreads();
#pragma unroll
    for (int kk = 0; kk < 2; ++kk) {
      frag8 ak[4], av[4], bb[4];
#pragma unroll
      for (int i = 0; i < 4; ++i) {
        ak[i] = frag_read64(Ak, wm + i * 16 + fr, kk, quad);
        av[i] = frag_read64(Av, wm + i * 16 + fr, kk, quad);
        bb[i] = frag_read64(Bs, wn + i * 16 + fr, kk, quad);
      }
#pragma unroll
      for (int mi = 0; mi < 4; ++mi)
#pragma unroll
        for (int ni = 0; ni < 4; ++ni) {
          acck[mi][ni] = __builtin_amdgcn_mfma_f32_16x16x32_bf16(ak[mi], bb[ni], acck[mi][ni], 0, 0, 0);
          accv[mi][ni] = __builtin_amdgcn_mfma_f32_16x16x32_bf16(av[mi], bb[ni], accv[mi][ni], 0, 0, 0);
        }
    }
    __syncthreads();
  }
#pragma unroll
  for (int mi = 0; mi < 4; ++mi)
#pragma unroll
    for (int r = 0; r < 4; ++r) {
      const int d = d0 + wm + mi * 16 + quad * 4 + r;
      const float bkv = bk[d], bvv = bv[d];
#pragma unroll
      for (int ni = 0; ni < 4; ++ni) {
        const int s = s0 + wn + ni * 16 + fr;
        const float ek = __expf(acck[mi][ni][r] + bkv);
        const float vv = accv[mi][ni][r] + bvv;
        const size_t idx = ((size_t)b * 512 + d) * 1024 + s;
        ekT[idx]  = f2bf(ek);
        ekvT[idx] = f2bf(ek * vv);
      }
    }
}

// ---------- AFT mixing: out = sigq * (EW@ekv) / (EW@ek), per batch ----------
// 8-phase-style schedule (T3+T4+T5): BM=256(t) x BN=128(d), BK=64, 512 thr =
// 8 waves (4Mx2N), per-wave 64x64 per matrix. Double-buffered 128 KiB LDS:
// per buffer  A ew[256x64] @0 | B1 ekv[128x64] @16384 | B2 ek[128x64] @24576.
// Per K-step: 4 phases {issue 2 stages for k+1 | ds_read subtile | s_barrier |
// lgkmcnt(0) | setprio(1) 16 MFMA setprio(0) | s_barrier}, counted vmcnt(2)
// only at end of P0 and P3 (loads stay in flight across barriers; never
// drain to 0 in the main loop). Staging issue order per step: A x4, B1 x2,
// B2 x2 -> end-P3 vmcnt(2) guarantees A+B1 of k+1 (needed at next P0) done
// with B2's 2 loads still outstanding; end-P0 vmcnt(2) retires them before
// P1 reads B2. Raw s_barrier (no implicit vmcnt-0 drain, unlike __syncthreads).
#define AFT_BUF (512 * 64)
__global__ __launch_bounds__(512, 2) void aft_kernel(const u16* __restrict__ ew,
                                                     const u16* __restrict__ ekT,
                                                     const u16* __restrict__ ekvT,
                                                     float* __restrict__ out) {
  __shared__ __align__(16) u16 lds[2 * AFT_BUF];   // 128 KiB
  const int tid = threadIdx.x;
  const int lane = tid & 63, wv = tid >> 6;
  const int wm = (wv >> 1) * 64;   // t-offset of wave: 0/64/128/192
  const int wn = (wv & 1) * 64;    // d-offset of wave: 0/64
  const int fr = lane & 15, quad = lane >> 4;
  const int d0 = blockIdx.x * 128;
  const int t0 = blockIdx.y * 256;
  const int b  = blockIdx.z;

  const u16* Ag  = ew + (size_t)t0 * 1024;
  const u16* B1g = ekvT + ((size_t)b * 512 + d0) * 1024;
  const u16* B2g = ekT  + ((size_t)b * 512 + d0) * 1024;

  f32x4 accn[4][4] = {}, accd[4][4] = {};

  // prologue: stage K-tile 0 into buffer 0 (issues: A x4, B1 x2, B2 x2)
#pragma unroll
  for (int i = 0; i < 4; ++i)
    stage64(Ag + (size_t)i * 64 * 1024, lds + i * 4096, tid);
#pragma unroll
  for (int i = 0; i < 2; ++i)
    stage64(B1g + (size_t)i * 64 * 1024, lds + 16384 + i * 4096, tid);
#pragma unroll
  for (int i = 0; i < 2; ++i)
    stage64(B2g + (size_t)i * 64 * 1024, lds + 24576 + i * 4096, tid);
  asm volatile("s_waitcnt vmcnt(0)" ::: "memory");
  __builtin_amdgcn_s_barrier();

  int cur = 0;
  for (int k = 0; k < 15; ++k) {
    u16* C  = lds + cur * AFT_BUF;
    u16* Nx = lds + (cur ^ 1) * AFT_BUF;
    const u16* An  = Ag  + (size_t)(k + 1) * 64;
    const u16* B1n = B1g + (size_t)(k + 1) * 64;
    const u16* B2n = B2g + (size_t)(k + 1) * 64;
    frag8 a[4], bb[4];

    // ---- P0: stage A0,A1(k+1) | read a(kk0), b1(kk0) | MFMA num kk0 ----
    stage64(An,                     Nx,        tid);
    stage64(An + (size_t)64 * 1024, Nx + 4096, tid);
#pragma unroll
    for (int i = 0; i < 4; ++i) a[i]  = frag_read64(C,         wm + i * 16 + fr, 0, quad);
#pragma unroll
    for (int i = 0; i < 4; ++i) bb[i] = frag_read64(C + 16384, wn + i * 16 + fr, 0, quad);
    __builtin_amdgcn_s_barrier();
    asm volatile("s_waitcnt lgkmcnt(0)" ::: "memory");
    __builtin_amdgcn_sched_barrier(0);
    __builtin_amdgcn_s_setprio(1);
#pragma unroll
    for (int mi = 0; mi < 4; ++mi)
#pragma unroll
      for (int ni = 0; ni < 4; ++ni)
        accn[mi][ni] = __builtin_amdgcn_mfma_f32_16x16x32_bf16(a[mi], bb[ni], accn[mi][ni], 0, 0, 0);
    __builtin_amdgcn_s_setprio(0);
    asm volatile("s_waitcnt vmcnt(2)" ::: "memory");   // retire prev-tile B2
    __builtin_amdgcn_s_barrier();

    // ---- P1: stage A2,A3(k+1) | read b2(kk0) | MFMA den kk0 ----
    stage64(An + (size_t)128 * 1024, Nx + 8192,  tid);
    stage64(An + (size_t)192 * 1024, Nx + 12288, tid);
#pragma unroll
    for (int i = 0; i < 4; ++i) bb[i] = frag_read64(C + 24576, wn + i * 16 + fr, 0, quad);
    __builtin_amdgcn_s_barrier();
    asm volatile("s_waitcnt lgkmcnt(0)" ::: "memory");
    __builtin_amdgcn_sched_barrier(0);
    __builtin_amdgcn_s_setprio(1);
#pragma unroll
    for (int mi = 0; mi < 4; ++mi)
#pragma unroll
      for (int ni = 0; ni < 4; ++ni)
        accd[mi][ni] = __builtin_amdgcn_mfma_f32_16x16x32_bf16(a[mi], bb[ni], accd[mi][ni], 0, 0, 0);
    __builtin_amdgcn_s_setprio(0);
    __builtin_amdgcn_s_barrier();

    // ---- P2: stage B1(k+1) | read a(kk1), b1(kk1) | MFMA num kk1 ----
    stage64(B1n,                     Nx + 16384, tid);
    stage64(B1n + (size_t)64 * 1024, Nx + 20480, tid);
#pragma unroll
    for (int i = 0; i < 4; ++i) a[i]  = frag_read64(C,         wm + i * 16 + fr, 1, quad);
#pragma unroll
    for (int i = 0; i < 4; ++i) bb[i] = frag_read64(C + 16384, wn + i * 16 + fr, 1, quad);
    __builtin_amdgcn_s_barrier();
    asm volatile("s_waitcnt lgkmcnt(0)" ::: "memory");
    __builtin_amdgcn_sched_barrier(0);
    __builtin_amdgcn_s_setprio(1);
#pragma unroll
    for (int mi = 0; mi < 4; ++mi)
#pragma unroll
      for (int ni = 0; ni < 4; ++ni)
        accn[mi][ni] = __builtin_amdgcn_mfma_f32_16x16x32_bf16(a[mi], bb[ni], accn[mi][ni], 0, 0, 0);
    __builtin_amdgcn_s_setprio(0);
    __builtin_amdgcn_s_barrier();

    // ---- P3: stage B2(k+1) | read b2(kk1) | MFMA den kk1 ----
    stage64(B2n,                     Nx + 24576, tid);
    stage64(B2n + (size_t)64 * 1024, Nx + 28672, tid);
#pragma unroll
    for (int i = 0; i < 4; ++i) bb[i] = frag_read64(C + 24576, wn + i * 16 + fr, 1, quad);
    __builtin_amdgcn_s_barrier();
    asm volatile("s_waitcnt lgkmcnt(0)" ::: "memory");
    __builtin_amdgcn_sched_barrier(0);
    __builtin_amdgcn_s_setprio(1);
#pragma unroll
    for (int mi = 0; mi < 4; ++mi)
#pragma unroll
      for (int ni = 0; ni < 4; ++ni)
        accd[mi][ni] = __builtin_amdgcn_mfma_f32_16x16x32_bf16(a[mi], bb[ni], accd[mi][ni], 0, 0, 0);
    __builtin_amdgcn_s_setprio(0);
    asm volatile("s_waitcnt vmcnt(2)" ::: "memory");   // A+B1 of k+1 done; B2 in flight
    __builtin_amdgcn_s_barrier();
    cur ^= 1;
  }

  // ---- last K-tile: fully staged; drain remaining B2 loads, then compute ----
  {
    u16* C = lds + cur * AFT_BUF;
    asm volatile("s_waitcnt vmcnt(0)" ::: "memory");
    __builtin_amdgcn_s_barrier();
#pragma unroll
    for (int kk = 0; kk < 2; ++kk) {
      frag8 a[4], b1[4], b2[4];
#pragma unroll
      for (int i = 0; i < 4; ++i) {
        a[i]  = frag_read64(C,         wm + i * 16 + fr, kk, quad);
        b1[i] = frag_read64(C + 16384, wn + i * 16 + fr, kk, quad);
        b2[i] = frag_read64(C + 24576, wn + i * 16 + fr, kk, quad);
      }
#pragma unroll
      for (int mi = 0; mi < 4; ++mi)
#pragma unroll
        for (int ni = 0; ni < 4; ++ni) {
          accn[mi][ni] = __builtin_amdgcn_mfma_f32_16x16x32_bf16(a[mi], b1[ni], accn[mi][ni], 0, 0, 0);
          accd[mi][ni] = __builtin_amdgcn_mfma_f32_16x16x32_bf16(a[mi], b2[ni], accd[mi][ni], 0, 0, 0);
        }
    }
  }

  // ---- epilogue: out = sigmoid(q) * num / den ----
#pragma unroll
  for (int mi = 0; mi < 4; ++mi)
#pragma unroll
    for (int ni = 0; ni < 4; ++ni)
#pragma unroll
      for (int r = 0; r < 4; ++r) {
        const int t = t0 + wm + mi * 16 + quad * 4 + r;
        const int d = d0 + wn + ni * 16 + fr;
        const size_t idx = ((size_t)b * 1024 + t) * 512 + d;
        const float sq = out[idx];                    // sigmoid(q) from q_kernel
        out[idx] = sq * accn[mi][ni][r] / accd[mi][ni][r];
      }
}

// ---------- launch ----------
// Workspace layout (bytes):
//   xb   bf16[32768][512]      @ 0          (32 MB)
//   wqb  bf16[512][512]        @ 33554432
//   wkb                        @ 34078720
//   wvb                        @ 34603008
//   ewb  bf16[1024][1024]      @ 35127296   (2 MB)
//   ekT  bf16[32][512][1024]   @ 37224448   (32 MB)
//   ekvT bf16[32][512][1024]   @ 70778880   (32 MB)
// total ≈ 99.5 MB. sigmoid(q) lives in d_out (read-then-overwrite in aft_kernel).
extern "C" void kernel_launch(void* const* d_in, const int* in_sizes, int n_in,
                              void* d_out, int out_size, void* d_ws, size_t ws_size,
                              hipStream_t stream) {
  const float* x  = (const float*)d_in[0];
  const float* Wq = (const float*)d_in[1];
  const float* bq = (const float*)d_in[2];
  const float* Wk = (const float*)d_in[3];
  const float* bk = (const float*)d_in[4];
  const float* Wv = (const float*)d_in[5];
  const float* bv = (const float*)d_in[6];
  const float* pb = (const float*)d_in[7];
  float* out = (float*)d_out;
  char* ws = (char*)d_ws;
  u16* xb   = (u16*)(ws);
  u16* wqb  = (u16*)(ws + 33554432);
  u16* wkb  = (u16*)(ws + 34078720);
  u16* wvb  = (u16*)(ws + 34603008);
  u16* ewb  = (u16*)(ws + 35127296);
  u16* ekT  = (u16*)(ws + 37224448);
  u16* ekvT = (u16*)(ws + 70778880);

  prep_kernel<<<18176, 256, 0, stream>>>(x, Wq, Wk, Wv, pb, xb, wqb, wkb, wvb, ewb);
  q_kernel<<<dim3(4, 256), 256, 0, stream>>>(xb, wqb, bq, out);
  kv_kernel<<<dim3(8, 4, 32), 256, 0, stream>>>(xb, wkb, wvb, bk, bv, ekT, ekvT);
  aft_kernel<<<dim3(4, 4, 32), 512, 0, stream>>>(ewb, ekT, ekvT, out);
}